// Round 11
// baseline (199.855 us; speedup 1.0000x reference)
//
#include <hip/hip_runtime.h>
#include <hip/hip_bf16.h>

// HyConv round 18 (instrumented): SPLIT build_gemm into gemm_k + build_k, phases
// byte-identical to round 14 (173.0us base). Rationale: 5 falsified theories in a
// row, and the two phase kernels (~106us, 60%) have NEVER surfaced in top-5 —
// build_gemm (63-72us) monopolizes it. With build_k and gemm_k each below the
// phases, next profile finally shows phase FETCH/VALU/Occupancy, plus clean
// standalone numbers for build and gemm (fusion value was never ablated).
// memset(ctr) -> gemm_k (1250) -> build_k (1250) -> phase1_pull -> phase2_pull

#define BB 4
#define NN 10000
#define MM 10000
#define EE 160000
#define CC 128
#define BM (BB * MM)   // 40000 hyperedge buckets
#define BN (BB * NN)   // 40000 node buckets
#define NCOPY 8
#define CAPX 16        // per-copy bucket capacity; per-copy deg ~ Poisson(2), P[>=17]~5e-11

typedef unsigned short u16;
using bf16 = __hip_bfloat16;
using bf162 = __hip_bfloat162;
typedef unsigned u32x4 __attribute__((ext_vector_type(4)));
typedef float f32x4 __attribute__((ext_vector_type(4)));

// ---------------- gemm_k: 1250 blocks, 32 rows x 128 cols; thread = 8r x 2c --------
__global__ __launch_bounds__(256) void gemm_k(const float* __restrict__ x,
                                              const float* __restrict__ theta,
                                              bf16* __restrict__ xt) {
    __shared__ float sTh[64 * 128];  // 32 KB
    __shared__ float sX[32 * 128];   // 16 KB
    const int tid = threadIdx.x;
    const int row0 = blockIdx.x * 32;  // rows 0..39968
    {
        const float4* src = (const float4*)&x[(size_t)row0 * 128];  // 1024 float4
        float4* dst = (float4*)sX;
#pragma unroll
        for (int i = 0; i < 4; ++i) dst[tid + 256 * i] = src[tid + 256 * i];
    }
    const int cg2 = (tid & 63) * 2;  // column pair base (0..126)
    const int rg = tid >> 6;         // row group 0..3
    float ax[8], ay[8];
#pragma unroll
    for (int r = 0; r < 8; ++r) { ax[r] = 0.f; ay[r] = 0.f; }

    for (int half = 0; half < 2; ++half) {
        __syncthreads();
        {
            const float4* src = (const float4*)&theta[half * 64 * 128];
            float4* dst = (float4*)sTh;
#pragma unroll
            for (int i = 0; i < 8; ++i) dst[tid + 256 * i] = src[tid + 256 * i];
        }
        __syncthreads();
#pragma unroll
        for (int k4 = 0; k4 < 16; ++k4) {
            const int kk = 4 * k4;
            const float2 t0 = *(const float2*)&sTh[(kk + 0) * 128 + cg2];
            const float2 t1 = *(const float2*)&sTh[(kk + 1) * 128 + cg2];
            const float2 t2 = *(const float2*)&sTh[(kk + 2) * 128 + cg2];
            const float2 t3 = *(const float2*)&sTh[(kk + 3) * 128 + cg2];
#pragma unroll
            for (int r = 0; r < 8; ++r) {
                const float4 xv =
                    *(const float4*)&sX[(rg * 8 + r) * 128 + half * 64 + kk];
                ax[r] = fmaf(xv.x, t0.x, ax[r]); ay[r] = fmaf(xv.x, t0.y, ay[r]);
                ax[r] = fmaf(xv.y, t1.x, ax[r]); ay[r] = fmaf(xv.y, t1.y, ay[r]);
                ax[r] = fmaf(xv.z, t2.x, ax[r]); ay[r] = fmaf(xv.z, t2.y, ay[r]);
                ax[r] = fmaf(xv.w, t3.x, ax[r]); ay[r] = fmaf(xv.w, t3.y, ay[r]);
            }
        }
    }
#pragma unroll
    for (int r = 0; r < 8; ++r) {
        bf162 h;
        h.x = __float2bfloat16(ax[r]);
        h.y = __float2bfloat16(ay[r]);
        *(bf162*)&xt[(size_t)(row0 + rg * 8 + r) * 128 + cg2] = h;
    }
}

// ---------------- build_k: 1250 blocks, 2 edges/thread, copy = bi & 7 --------------
__global__ __launch_bounds__(256) void build_k(const int* __restrict__ H,
                                               int* __restrict__ ctr,
                                               u16* __restrict__ srcA,
                                               u16* __restrict__ srcB) {
    const int bi = blockIdx.x;
    const int gidx = bi * 256 + threadIdx.x;     // 0..319,999
    const int g0 = gidx * 2;                     // even edge id, pair in same batch
    const int cp = bi & 7;
    const int b = g0 / EE, e = g0 - b * EE;
    const int2 nd2 = *(const int2*)&H[b * 2 * EE + e];
    const int2 he2 = *(const int2*)&H[b * 2 * EE + EE + e];
    {
        const int bktA = b * MM + he2.x;
        const int s = atomicAdd(&ctr[cp * (BM + BN) + bktA], 1);
        if (s < CAPX) srcA[((size_t)cp * BM + bktA) * CAPX + s] = (u16)nd2.x;
        const int bktB = b * NN + nd2.x;
        const int q = atomicAdd(&ctr[cp * (BM + BN) + BM + bktB], 1);
        if (q < CAPX) srcB[((size_t)cp * BN + bktB) * CAPX + q] = (u16)he2.x;
    }
    {
        const int bktA = b * MM + he2.y;
        const int s = atomicAdd(&ctr[cp * (BM + BN) + bktA], 1);
        if (s < CAPX) srcA[((size_t)cp * BM + bktA) * CAPX + s] = (u16)nd2.y;
        const int bktB = b * NN + nd2.y;
        const int q = atomicAdd(&ctr[cp * (BM + BN) + BM + bktB], 1);
        if (q < CAPX) srcB[((size_t)cp * BN + bktB) * CAPX + q] = (u16)he2.y;
    }
}

// ---------------- bf16-pair helpers ----------------
__device__ __forceinline__ float blo(unsigned w) { return __uint_as_float(w << 16); }
__device__ __forceinline__ float bhi(unsigned w) { return __uint_as_float(w & 0xffff0000u); }
__device__ __forceinline__ unsigned pk2(float a, float b) {
    bf162 h;
    h.x = __float2bfloat16(a);
    h.y = __float2bfloat16(b);
    return *(unsigned*)&h;
}

// accumulate 8 channels from a 16B chunk of one row
__device__ __forceinline__ void acc8(const uint4 pk, float* s) {
    s[0] += blo(pk.x); s[1] += bhi(pk.x);
    s[2] += blo(pk.y); s[3] += bhi(pk.y);
    s[4] += blo(pk.z); s[5] += bhi(pk.z);
    s[6] += blo(pk.w); s[7] += bhi(pk.w);
}

// batched swizzle: batch b -> XCD pair {2b,2b+1}; jj = 16-bucket group id (0..624).
__device__ __forceinline__ bool swz_grp(int blk, int& b, int& jj) {
    const int xcd = blk & 7;
    b = xcd >> 1;
    jj = ((blk >> 3) << 1) | (xcd & 1);
    return jj < 625;
}

// ---------------- phase1: batched x4 — gather A, publish flat B (r14-identical) -----
__global__ __launch_bounds__(256) void phase1_pull(const bf16* __restrict__ xt,
                                                   const int* __restrict__ ctr,
                                                   const u16* __restrict__ srcA,
                                                   const u16* __restrict__ srcB,
                                                   u16* __restrict__ flatB,
                                                   int* __restrict__ cntB,
                                                   bf16* __restrict__ x_edge) {
    __shared__ __align__(16) u16 slot[4][8 * 64];  // 4 waves x 8 slots x 64 entries
    __shared__ u16 hdr[4][8];                      // per-slot totals
    int b, jj;
    if (!swz_grp(blockIdx.x, b, jj)) return;       // uniform per block
    const int w4 = threadIdx.x >> 6;
    const int lane = threadIdx.x & 63;
    const int wl0 = jj * 16 + w4 * 4;              // first of this wave's 4 buckets
    u16* sb = slot[w4];
    u16* hd = hdr[w4];

    // ---- one-volley merge: lane=(t,c): t=lane>>3 slot (0-3:A, 4-7:B), c=copy ----
    const int t = lane >> 3, c = lane & 7;
    const bool isA = t < 4;
    const int wl = wl0 + (isA ? t : t - 4);
    const int wid = (isA ? b * MM : b * NN) + wl;
    const u16* lst = isA ? (srcA + ((size_t)c * BM + wid) * CAPX)
                         : (srcB + ((size_t)c * BN + wid) * CAPX);
    const uint4 f0 = *(const uint4*)lst;           // entries 0..7
    const uint4 f1 = *(const uint4*)(lst + 8);     // entries 8..15
    int cnt = ctr[c * (BM + BN) + (isA ? wid : BM + wid)];
    cnt = cnt > CAPX ? CAPX : cnt;
    int pre = cnt;                                 // inclusive prefix within 8-group
#pragma unroll
    for (int d = 1; d < 8; d <<= 1) {
        const int o = __shfl_up(pre, d, 8);
        if (c >= d) pre += o;
    }
    const int base = pre - cnt;
    if (c == 7) hd[t] = (u16)(pre > 64 ? 64 : pre);
    {
        const unsigned wd[8] = {f0.x, f0.y, f0.z, f0.w, f1.x, f1.y, f1.z, f1.w};
#pragma unroll
        for (int j = 0; j < CAPX; ++j) {
            const u16 v = (u16)((j & 1) ? (wd[j >> 1] >> 16) : (wd[j >> 1] & 0xffffu));
            const int p = base + j;
            if (j < cnt && p < 64) sb[t * 64 + p] = v;
        }
    }
    __syncthreads();

    // ---- publish flat B records (4 x 128B + counts), consumer-local dirty ----
    if (lane < 32) {
        const int tb = lane >> 3, h = lane & 7;
        const int widB = b * NN + wl0 + tb;
        *(u32x4*)&flatB[(size_t)widB * 64 + h * 8] =
            *(const u32x4*)&sb[(4 + tb) * 64 + h * 8];
        if (h == 0) cntB[widB] = hd[4 + tb];
    }

    // ---- batched gather: 4 A-buckets back-to-back ----
    const bf16* bas = xt + (size_t)b * NN * CC;
    const int g = lane >> 4, c16 = lane & 15;
    const int T0 = hd[0], T1 = hd[1], T2 = hd[2], T3 = hd[3];
    float s0[8], s1[8], s2[8], s3[8];
#pragma unroll
    for (int k = 0; k < 8; ++k) { s0[k] = 0.f; s1[k] = 0.f; s2[k] = 0.f; s3[k] = 0.f; }
#define GATH(SS, TT, TOT)                                                              \
    {                                                                                  \
        int i = 0;                                                                     \
        for (; i + 4 <= (TOT); i += 4) {                                               \
            const int ix = sb[(TT)*64 + i + g];                                        \
            const uint4 pk = *(const uint4*)(bas + (size_t)ix * CC + c16 * 8);         \
            acc8(pk, SS);                                                              \
        }                                                                              \
        if (i < (TOT) && g < (TOT)-i) {                                                \
            const int ix = sb[(TT)*64 + i + g];                                        \
            const uint4 pk = *(const uint4*)(bas + (size_t)ix * CC + c16 * 8);         \
            acc8(pk, SS);                                                              \
        }                                                                              \
    }
    GATH(s0, 0, T0)
    GATH(s1, 1, T1)
    GATH(s2, 2, T2)
    GATH(s3, 3, T3)
#undef GATH

#define REDST(SS, TT, TOT)                                                             \
    {                                                                                  \
        _Pragma("unroll") for (int k = 0; k < 8; ++k) {                                \
            SS[k] += __shfl_xor(SS[k], 16, 64);                                        \
            SS[k] += __shfl_xor(SS[k], 32, 64);                                        \
        }                                                                              \
        const float w = (TOT) ? 1.0f / (float)(TOT) : 0.f;                             \
        if (g == 0) {                                                                  \
            u32x4 o;                                                                   \
            o.x = pk2(SS[0] * w, SS[1] * w);                                           \
            o.y = pk2(SS[2] * w, SS[3] * w);                                           \
            o.z = pk2(SS[4] * w, SS[5] * w);                                           \
            o.w = pk2(SS[6] * w, SS[7] * w);                                           \
            *(u32x4*)&x_edge[(size_t)(b * MM + wl0 + (TT)) * CC + c16 * 8] = o;        \
        }                                                                              \
    }
    REDST(s0, 0, T0)
    REDST(s1, 1, T1)
    REDST(s2, 2, T2)
    REDST(s3, 3, T3)
#undef REDST
}

// ---------------- phase2: batched x4 — gather from x_edge + bias (r14-identical) ----
__global__ __launch_bounds__(256) void phase2_pull(const bf16* __restrict__ x_edge,
                                                   const u16* __restrict__ flatB,
                                                   const int* __restrict__ cntB,
                                                   const float* __restrict__ bias,
                                                   float* __restrict__ out) {
    __shared__ __align__(16) u16 slot[4][4 * 64];
    __shared__ int hdr[4][4];
    int b, jj;
    if (!swz_grp(blockIdx.x, b, jj)) return;
    const int w4 = threadIdx.x >> 6;
    const int lane = threadIdx.x & 63;
    const int wl0 = jj * 16 + w4 * 4;
    u16* sb = slot[w4];
    int* hd = hdr[w4];

    // one-volley record load: 4 records x 128B by 32 lanes + 4 counts
    if (lane < 32) {
        const int tb = lane >> 3, h = lane & 7;
        const int wid = b * NN + wl0 + tb;
        *(u32x4*)&sb[tb * 64 + h * 8] =
            *(const u32x4*)&flatB[(size_t)wid * 64 + h * 8];
        if (h == 0) hd[tb] = cntB[wid];
    }
    __syncthreads();

    const bf16* bas = x_edge + (size_t)b * MM * CC;
    const int g = lane >> 4, c16 = lane & 15;
    const int T0 = hd[0], T1 = hd[1], T2 = hd[2], T3 = hd[3];
    float s0[8], s1[8], s2[8], s3[8];
#pragma unroll
    for (int k = 0; k < 8; ++k) { s0[k] = 0.f; s1[k] = 0.f; s2[k] = 0.f; s3[k] = 0.f; }
#define GATH(SS, TT, TOT)                                                              \
    {                                                                                  \
        int i = 0;                                                                     \
        for (; i + 4 <= (TOT); i += 4) {                                               \
            const int ix = sb[(TT)*64 + i + g];                                        \
            const uint4 pk = *(const uint4*)(bas + (size_t)ix * CC + c16 * 8);         \
            acc8(pk, SS);                                                              \
        }                                                                              \
        if (i < (TOT) && g < (TOT)-i) {                                                \
            const int ix = sb[(TT)*64 + i + g];                                        \
            const uint4 pk = *(const uint4*)(bas + (size_t)ix * CC + c16 * 8);         \
            acc8(pk, SS);                                                              \
        }                                                                              \
    }
    GATH(s0, 0, T0)
    GATH(s1, 1, T1)
    GATH(s2, 2, T2)
    GATH(s3, 3, T3)
#undef GATH

    const float4 bv = *(const float4*)&bias[c16 * 8 + (g & 1) * 4];  // used by g<2
#define REDST(SS, TT, TOT)                                                             \
    {                                                                                  \
        _Pragma("unroll") for (int k = 0; k < 8; ++k) {                                \
            SS[k] += __shfl_xor(SS[k], 16, 64);                                        \
            SS[k] += __shfl_xor(SS[k], 32, 64);                                        \
        }                                                                              \
        const float w = (TOT) ? 1.0f / (float)(TOT) : 0.f;                             \
        if (g < 2) {                                                                   \
            f32x4 o;                                                                   \
            if (g == 0) {                                                              \
                o.x = SS[0] * w + bv.x; o.y = SS[1] * w + bv.y;                        \
                o.z = SS[2] * w + bv.z; o.w = SS[3] * w + bv.w;                        \
            } else {                                                                   \
                o.x = SS[4] * w + bv.x; o.y = SS[5] * w + bv.y;                        \
                o.z = SS[6] * w + bv.z; o.w = SS[7] * w + bv.w;                        \
            }                                                                          \
            __builtin_nontemporal_store(                                               \
                o, (f32x4*)&out[(size_t)(b * NN + wl0 + (TT)) * CC + c16 * 8 + g * 4]);\
        }                                                                              \
    }
    REDST(s0, 0, T0)
    REDST(s1, 1, T1)
    REDST(s2, 2, T2)
    REDST(s3, 3, T3)
#undef REDST
}

extern "C" void kernel_launch(void* const* d_in, const int* in_sizes, int n_in,
                              void* d_out, int out_size, void* d_ws, size_t ws_size,
                              hipStream_t stream) {
    const float* x = (const float*)d_in[0];
    const int* H = (const int*)d_in[1];
    const float* theta = (const float*)d_in[2];
    const float* bias = (const float*)d_in[3];
    float* out = (float*)d_out;

    // workspace (~48.8 MB): xt | x_edge | ctr | srcA | srcB | flatB | cntB
    bf16* xt = (bf16*)d_ws;                                   // 10.24 MB
    bf16* x_edge = xt + (size_t)BB * NN * CC;                 // 10.24 MB
    int* ctr = (int*)(x_edge + (size_t)BB * MM * CC);         // 2.56 MB
    u16* srcA = (u16*)(ctr + NCOPY * (BM + BN));              // 10.24 MB
    u16* srcB = srcA + (size_t)NCOPY * BM * CAPX;             // 10.24 MB
    u16* flatB = srcB + (size_t)NCOPY * BN * CAPX;            // 5.12 MB
    int* cntB = (int*)(flatB + (size_t)BN * 64);              // 0.16 MB

    (void)hipMemsetAsync(ctr, 0, (size_t)NCOPY * (BM + BN) * sizeof(int), stream);

    gemm_k<<<1250, 256, 0, stream>>>(x, theta, xt);
    build_k<<<1250, 256, 0, stream>>>(H, ctr, srcA, srcB);
    phase1_pull<<<2504, 256, 0, stream>>>(xt, ctr, srcA, srcB, flatB, cntB, x_edge);
    phase2_pull<<<2504, 256, 0, stream>>>(x_edge, flatB, cntB, bias, out);
}

// Round 12
// 167.959 us; speedup vs baseline: 1.1899x; 1.1899x over previous
//
#include <hip/hip_runtime.h>
#include <hip/hip_bf16.h>

// HyConv round 19: r14 fused config (173.0us proven; fusion validated by r18 ablation:
// build_k alone=70us > fused build+gemm=63.5us) + ONE change: TRANSPOSED list layouts.
//   ctr:  [copy][bucket] -> [bucket][copy]  (8 ctrs = 32 contiguous B = 1 request)
//   srcA/B: [copy][bucket][16] -> [bucket][copy][16] (8 frags = 256 contiguous B)
// Round-18's model: all kernels bound by random 64B L2-request rate (~64G/s chip);
// the merge volley was 24 req/bucket-side purely because copies were MB apart.
// Transpose cuts it to 9 (-1.2M req ~= -19us predicted on p1). Build atomic/store
// counts unchanged. Everything else byte-identical to round 14.
// memset(ctr) -> build_gemm -> phase1_pull(+flatB publish) -> phase2_pull

#define BB 4
#define NN 10000
#define MM 10000
#define EE 160000
#define CC 128
#define BM (BB * MM)   // 40000 hyperedge buckets
#define BN (BB * NN)   // 40000 node buckets
#define NCOPY 8
#define CAPX 16        // per-copy bucket capacity; per-copy deg ~ Poisson(2), P[>=17]~5e-11

typedef unsigned short u16;
using bf16 = __hip_bfloat16;
using bf162 = __hip_bfloat162;
typedef unsigned u32x4 __attribute__((ext_vector_type(4)));
typedef float f32x4 __attribute__((ext_vector_type(4)));

// ---------------- fused: gemm ((bi>>3)&1==0) || build ((bi>>3)&1==1) ----------------
// grid = 2512: 1250 gemm blocks (32 rows each), 1250 build blocks (2 edges/thread).
__global__ __launch_bounds__(256) void build_gemm_k(const int* __restrict__ H,
                                                    int* __restrict__ ctr,
                                                    u16* __restrict__ srcA,
                                                    u16* __restrict__ srcB,
                                                    const float* __restrict__ x,
                                                    const float* __restrict__ theta,
                                                    bf16* __restrict__ xt) {
    __shared__ float sTh[64 * 128];  // 32 KB
    __shared__ float sX[32 * 128];   // 16 KB
    const int bi = blockIdx.x;
    const int idx = (bi >> 4) * 8 + (bi & 7);  // index within class, XCD-uniform

    if ((bi >> 3) & 1) {
        // ---- build: 2 edges per thread, XCD-local copy = bi & 7 ----
        if (idx >= 1250) return;
        const int gidx = idx * 256 + threadIdx.x;    // 0..319,999
        const int g0 = gidx * 2;                     // even edge id, pair in same batch
        const int cp = bi & 7;
        const int b = g0 / EE, e = g0 - b * EE;
        const int2 nd2 = *(const int2*)&H[b * 2 * EE + e];
        const int2 he2 = *(const int2*)&H[b * 2 * EE + EE + e];
        {
            const int bktA = b * MM + he2.x;
            const int s = atomicAdd(&ctr[bktA * NCOPY + cp], 1);
            if (s < CAPX) srcA[((size_t)bktA * NCOPY + cp) * CAPX + s] = (u16)nd2.x;
            const int bktB = b * NN + nd2.x;
            const int q = atomicAdd(&ctr[BM * NCOPY + bktB * NCOPY + cp], 1);
            if (q < CAPX) srcB[((size_t)bktB * NCOPY + cp) * CAPX + q] = (u16)he2.x;
        }
        {
            const int bktA = b * MM + he2.y;
            const int s = atomicAdd(&ctr[bktA * NCOPY + cp], 1);
            if (s < CAPX) srcA[((size_t)bktA * NCOPY + cp) * CAPX + s] = (u16)nd2.y;
            const int bktB = b * NN + nd2.y;
            const int q = atomicAdd(&ctr[BM * NCOPY + bktB * NCOPY + cp], 1);
            if (q < CAPX) srcB[((size_t)bktB * NCOPY + cp) * CAPX + q] = (u16)he2.y;
        }
        return;
    }

    // ---- gemm: 32 rows x 128 cols per block; thread = 8 rows x 2 cols ----
    if (idx >= 1250) return;
    const int tid = threadIdx.x;
    const int row0 = idx * 32;  // rows 0..39968
    {
        const float4* src = (const float4*)&x[(size_t)row0 * 128];  // 1024 float4
        float4* dst = (float4*)sX;
#pragma unroll
        for (int i = 0; i < 4; ++i) dst[tid + 256 * i] = src[tid + 256 * i];
    }
    const int cg2 = (tid & 63) * 2;  // column pair base (0..126)
    const int rg = tid >> 6;         // row group 0..3
    float ax[8], ay[8];
#pragma unroll
    for (int r = 0; r < 8; ++r) { ax[r] = 0.f; ay[r] = 0.f; }

    for (int half = 0; half < 2; ++half) {
        __syncthreads();
        {
            const float4* src = (const float4*)&theta[half * 64 * 128];
            float4* dst = (float4*)sTh;
#pragma unroll
            for (int i = 0; i < 8; ++i) dst[tid + 256 * i] = src[tid + 256 * i];
        }
        __syncthreads();
#pragma unroll
        for (int k4 = 0; k4 < 16; ++k4) {
            const int kk = 4 * k4;
            const float2 t0 = *(const float2*)&sTh[(kk + 0) * 128 + cg2];
            const float2 t1 = *(const float2*)&sTh[(kk + 1) * 128 + cg2];
            const float2 t2 = *(const float2*)&sTh[(kk + 2) * 128 + cg2];
            const float2 t3 = *(const float2*)&sTh[(kk + 3) * 128 + cg2];
#pragma unroll
            for (int r = 0; r < 8; ++r) {
                const float4 xv =
                    *(const float4*)&sX[(rg * 8 + r) * 128 + half * 64 + kk];
                ax[r] = fmaf(xv.x, t0.x, ax[r]); ay[r] = fmaf(xv.x, t0.y, ay[r]);
                ax[r] = fmaf(xv.y, t1.x, ax[r]); ay[r] = fmaf(xv.y, t1.y, ay[r]);
                ax[r] = fmaf(xv.z, t2.x, ax[r]); ay[r] = fmaf(xv.z, t2.y, ay[r]);
                ax[r] = fmaf(xv.w, t3.x, ax[r]); ay[r] = fmaf(xv.w, t3.y, ay[r]);
            }
        }
    }
#pragma unroll
    for (int r = 0; r < 8; ++r) {
        bf162 h;
        h.x = __float2bfloat16(ax[r]);
        h.y = __float2bfloat16(ay[r]);
        *(bf162*)&xt[(size_t)(row0 + rg * 8 + r) * 128 + cg2] = h;
    }
}

// ---------------- bf16-pair helpers ----------------
__device__ __forceinline__ float blo(unsigned w) { return __uint_as_float(w << 16); }
__device__ __forceinline__ float bhi(unsigned w) { return __uint_as_float(w & 0xffff0000u); }
__device__ __forceinline__ unsigned pk2(float a, float b) {
    bf162 h;
    h.x = __float2bfloat16(a);
    h.y = __float2bfloat16(b);
    return *(unsigned*)&h;
}

// accumulate 8 channels from a 16B chunk of one row
__device__ __forceinline__ void acc8(const uint4 pk, float* s) {
    s[0] += blo(pk.x); s[1] += bhi(pk.x);
    s[2] += blo(pk.y); s[3] += bhi(pk.y);
    s[4] += blo(pk.z); s[5] += bhi(pk.z);
    s[6] += blo(pk.w); s[7] += bhi(pk.w);
}

// batched swizzle: batch b -> XCD pair {2b,2b+1}; jj = 16-bucket group id (0..624).
__device__ __forceinline__ bool swz_grp(int blk, int& b, int& jj) {
    const int xcd = blk & 7;
    b = xcd >> 1;
    jj = ((blk >> 3) << 1) | (xcd & 1);
    return jj < 625;
}

// ---------------- phase1: batched x4 — gather A, publish flat B ----------------
__global__ __launch_bounds__(256) void phase1_pull(const bf16* __restrict__ xt,
                                                   const int* __restrict__ ctr,
                                                   const u16* __restrict__ srcA,
                                                   const u16* __restrict__ srcB,
                                                   u16* __restrict__ flatB,
                                                   int* __restrict__ cntB,
                                                   bf16* __restrict__ x_edge) {
    __shared__ __align__(16) u16 slot[4][8 * 64];  // 4 waves x 8 slots x 64 entries
    __shared__ u16 hdr[4][8];                      // per-slot totals
    int b, jj;
    if (!swz_grp(blockIdx.x, b, jj)) return;       // uniform per block
    const int w4 = threadIdx.x >> 6;
    const int lane = threadIdx.x & 63;
    const int wl0 = jj * 16 + w4 * 4;              // first of this wave's 4 buckets
    u16* sb = slot[w4];
    u16* hd = hdr[w4];

    // ---- one-volley merge: lane=(t,c). TRANSPOSED layout: bucket's 8 ctrs are
    //      32 contiguous B (1 req), 8 frags are 256 contiguous B (4 req/instr). ----
    const int t = lane >> 3, c = lane & 7;
    const bool isA = t < 4;
    const int wl = wl0 + (isA ? t : t - 4);
    const int wid = (isA ? b * MM : b * NN) + wl;
    const u16* lst = isA ? (srcA + ((size_t)wid * NCOPY + c) * CAPX)
                         : (srcB + ((size_t)wid * NCOPY + c) * CAPX);
    const uint4 f0 = *(const uint4*)lst;           // entries 0..7
    const uint4 f1 = *(const uint4*)(lst + 8);     // entries 8..15
    int cnt = ctr[(isA ? wid * NCOPY : BM * NCOPY + wid * NCOPY) + c];
    cnt = cnt > CAPX ? CAPX : cnt;
    int pre = cnt;                                 // inclusive prefix within 8-group
#pragma unroll
    for (int d = 1; d < 8; d <<= 1) {
        const int o = __shfl_up(pre, d, 8);
        if (c >= d) pre += o;
    }
    const int base = pre - cnt;
    if (c == 7) hd[t] = (u16)(pre > 64 ? 64 : pre);
    {
        const unsigned wd[8] = {f0.x, f0.y, f0.z, f0.w, f1.x, f1.y, f1.z, f1.w};
#pragma unroll
        for (int j = 0; j < CAPX; ++j) {
            const u16 v = (u16)((j & 1) ? (wd[j >> 1] >> 16) : (wd[j >> 1] & 0xffffu));
            const int p = base + j;
            if (j < cnt && p < 64) sb[t * 64 + p] = v;
        }
    }
    __syncthreads();

    // ---- publish flat B records (4 x 128B + counts), consumer-local dirty ----
    if (lane < 32) {
        const int tb = lane >> 3, h = lane & 7;
        const int widB = b * NN + wl0 + tb;
        *(u32x4*)&flatB[(size_t)widB * 64 + h * 8] =
            *(const u32x4*)&sb[(4 + tb) * 64 + h * 8];
        if (h == 0) cntB[widB] = hd[4 + tb];
    }

    // ---- batched gather: 4 A-buckets back-to-back ----
    const bf16* bas = xt + (size_t)b * NN * CC;
    const int g = lane >> 4, c16 = lane & 15;
    const int T0 = hd[0], T1 = hd[1], T2 = hd[2], T3 = hd[3];
    float s0[8], s1[8], s2[8], s3[8];
#pragma unroll
    for (int k = 0; k < 8; ++k) { s0[k] = 0.f; s1[k] = 0.f; s2[k] = 0.f; s3[k] = 0.f; }
#define GATH(SS, TT, TOT)                                                              \
    {                                                                                  \
        int i = 0;                                                                     \
        for (; i + 4 <= (TOT); i += 4) {                                               \
            const int ix = sb[(TT)*64 + i + g];                                        \
            const uint4 pk = *(const uint4*)(bas + (size_t)ix * CC + c16 * 8);         \
            acc8(pk, SS);                                                              \
        }                                                                              \
        if (i < (TOT) && g < (TOT)-i) {                                                \
            const int ix = sb[(TT)*64 + i + g];                                        \
            const uint4 pk = *(const uint4*)(bas + (size_t)ix * CC + c16 * 8);         \
            acc8(pk, SS);                                                              \
        }                                                                              \
    }
    GATH(s0, 0, T0)
    GATH(s1, 1, T1)
    GATH(s2, 2, T2)
    GATH(s3, 3, T3)
#undef GATH

#define REDST(SS, TT, TOT)                                                             \
    {                                                                                  \
        _Pragma("unroll") for (int k = 0; k < 8; ++k) {                                \
            SS[k] += __shfl_xor(SS[k], 16, 64);                                        \
            SS[k] += __shfl_xor(SS[k], 32, 64);                                        \
        }                                                                              \
        const float w = (TOT) ? 1.0f / (float)(TOT) : 0.f;                             \
        if (g == 0) {                                                                  \
            u32x4 o;                                                                   \
            o.x = pk2(SS[0] * w, SS[1] * w);                                           \
            o.y = pk2(SS[2] * w, SS[3] * w);                                           \
            o.z = pk2(SS[4] * w, SS[5] * w);                                           \
            o.w = pk2(SS[6] * w, SS[7] * w);                                           \
            *(u32x4*)&x_edge[(size_t)(b * MM + wl0 + (TT)) * CC + c16 * 8] = o;        \
        }                                                                              \
    }
    REDST(s0, 0, T0)
    REDST(s1, 1, T1)
    REDST(s2, 2, T2)
    REDST(s3, 3, T3)
#undef REDST
}

// ---------------- phase2: batched x4 — gather from x_edge + bias (r14-identical) ----
__global__ __launch_bounds__(256) void phase2_pull(const bf16* __restrict__ x_edge,
                                                   const u16* __restrict__ flatB,
                                                   const int* __restrict__ cntB,
                                                   const float* __restrict__ bias,
                                                   float* __restrict__ out) {
    __shared__ __align__(16) u16 slot[4][4 * 64];
    __shared__ int hdr[4][4];
    int b, jj;
    if (!swz_grp(blockIdx.x, b, jj)) return;
    const int w4 = threadIdx.x >> 6;
    const int lane = threadIdx.x & 63;
    const int wl0 = jj * 16 + w4 * 4;
    u16* sb = slot[w4];
    int* hd = hdr[w4];

    // one-volley record load: 4 records x 128B by 32 lanes + 4 counts
    if (lane < 32) {
        const int tb = lane >> 3, h = lane & 7;
        const int wid = b * NN + wl0 + tb;
        *(u32x4*)&sb[tb * 64 + h * 8] =
            *(const u32x4*)&flatB[(size_t)wid * 64 + h * 8];
        if (h == 0) hd[tb] = cntB[wid];
    }
    __syncthreads();

    const bf16* bas = x_edge + (size_t)b * MM * CC;
    const int g = lane >> 4, c16 = lane & 15;
    const int T0 = hd[0], T1 = hd[1], T2 = hd[2], T3 = hd[3];
    float s0[8], s1[8], s2[8], s3[8];
#pragma unroll
    for (int k = 0; k < 8; ++k) { s0[k] = 0.f; s1[k] = 0.f; s2[k] = 0.f; s3[k] = 0.f; }
#define GATH(SS, TT, TOT)                                                              \
    {                                                                                  \
        int i = 0;                                                                     \
        for (; i + 4 <= (TOT); i += 4) {                                               \
            const int ix = sb[(TT)*64 + i + g];                                        \
            const uint4 pk = *(const uint4*)(bas + (size_t)ix * CC + c16 * 8);         \
            acc8(pk, SS);                                                              \
        }                                                                              \
        if (i < (TOT) && g < (TOT)-i) {                                                \
            const int ix = sb[(TT)*64 + i + g];                                        \
            const uint4 pk = *(const uint4*)(bas + (size_t)ix * CC + c16 * 8);         \
            acc8(pk, SS);                                                              \
        }                                                                              \
    }
    GATH(s0, 0, T0)
    GATH(s1, 1, T1)
    GATH(s2, 2, T2)
    GATH(s3, 3, T3)
#undef GATH

    const float4 bv = *(const float4*)&bias[c16 * 8 + (g & 1) * 4];  // used by g<2
#define REDST(SS, TT, TOT)                                                             \
    {                                                                                  \
        _Pragma("unroll") for (int k = 0; k < 8; ++k) {                                \
            SS[k] += __shfl_xor(SS[k], 16, 64);                                        \
            SS[k] += __shfl_xor(SS[k], 32, 64);                                        \
        }                                                                              \
        const float w = (TOT) ? 1.0f / (float)(TOT) : 0.f;                             \
        if (g < 2) {                                                                   \
            f32x4 o;                                                                   \
            if (g == 0) {                                                              \
                o.x = SS[0] * w + bv.x; o.y = SS[1] * w + bv.y;                        \
                o.z = SS[2] * w + bv.z; o.w = SS[3] * w + bv.w;                        \
            } else {                                                                   \
                o.x = SS[4] * w + bv.x; o.y = SS[5] * w + bv.y;                        \
                o.z = SS[6] * w + bv.z; o.w = SS[7] * w + bv.w;                        \
            }                                                                          \
            __builtin_nontemporal_store(                                               \
                o, (f32x4*)&out[(size_t)(b * NN + wl0 + (TT)) * CC + c16 * 8 + g * 4]);\
        }                                                                              \
    }
    REDST(s0, 0, T0)
    REDST(s1, 1, T1)
    REDST(s2, 2, T2)
    REDST(s3, 3, T3)
#undef REDST
}

extern "C" void kernel_launch(void* const* d_in, const int* in_sizes, int n_in,
                              void* d_out, int out_size, void* d_ws, size_t ws_size,
                              hipStream_t stream) {
    const float* x = (const float*)d_in[0];
    const int* H = (const int*)d_in[1];
    const float* theta = (const float*)d_in[2];
    const float* bias = (const float*)d_in[3];
    float* out = (float*)d_out;

    // workspace (~48.8 MB): xt | x_edge | ctr | srcA | srcB | flatB | cntB
    bf16* xt = (bf16*)d_ws;                                   // 10.24 MB
    bf16* x_edge = xt + (size_t)BB * NN * CC;                 // 10.24 MB
    int* ctr = (int*)(x_edge + (size_t)BB * MM * CC);         // 2.56 MB
    u16* srcA = (u16*)(ctr + NCOPY * (BM + BN));              // 10.24 MB
    u16* srcB = srcA + (size_t)NCOPY * BM * CAPX;             // 10.24 MB
    u16* flatB = srcB + (size_t)NCOPY * BN * CAPX;            // 5.12 MB
    int* cntB = (int*)(flatB + (size_t)BN * 64);              // 0.16 MB

    (void)hipMemsetAsync(ctr, 0, (size_t)NCOPY * (BM + BN) * sizeof(int), stream);

    build_gemm_k<<<2512, 256, 0, stream>>>(H, ctr, srcA, srcB, x, theta, xt);
    phase1_pull<<<2504, 256, 0, stream>>>(xt, ctr, srcA, srcB, flatB, cntB, x_edge);
    phase2_pull<<<2504, 256, 0, stream>>>(x_edge, flatB, cntB, bias, out);
}